// Round 9
// baseline (65.440 us; speedup 1.0000x reference)
//
#include <hip/hip_runtime.h>
#include <stdint.h>

#define N_OUT    4096
#define N_IN     4096
#define TOKENS   256
#define N_SPARSE 8388608
#define SPLITK   8
#define KCHUNK   256               // gather chunk width
#define NCHUNK   2                 // chunks per block -> block K-span 512
#define NSEG     (N_IN / KCHUNK)   // 16 segments
#define CPW      (NSEG + 1)        // 17 col_ptr entries per row
#define BN       64

typedef __attribute__((ext_vector_type(8))) short bf16x8;
typedef __attribute__((ext_vector_type(8))) unsigned short u16x8;
typedef __attribute__((ext_vector_type(4))) float f32x4;

__device__ __forceinline__ unsigned short f2bf(float f) {
    union { float f; unsigned u; } v; v.f = f;
    unsigned r = v.u + 0x7fffu + ((v.u >> 16) & 1u);   // RNE
    return (unsigned short)(r >> 16);
}

__device__ __forceinline__ float bf2f(unsigned short u) {
    union { unsigned u; float f; } v; v.u = ((unsigned)u) << 16;
    return v.f;
}

// ---- kernel 1 (merged): convert x->bf16  +  col_ptr binary searches -------
// Blocks [0,1024): xb[i] = bf16(x[i]), 4 elems/thread.
// Blocks [1024,1296): cp[r*17+z] = lower_bound(idx, r*N_IN + z*KCHUNK).
__global__ void prep(const float* __restrict__ x, const int* __restrict__ idx,
                     unsigned short* __restrict__ xb, int* __restrict__ cp) {
    const int b = blockIdx.x;
    const int t = threadIdx.x;
    if (b < 1024) {
        const int i = (b * 256 + t) * 4;
        const float4 v = *(const float4*)(x + i);
        ushort4 o;
        o.x = f2bf(v.x); o.y = f2bf(v.y); o.z = f2bf(v.z); o.w = f2bf(v.w);
        *(ushort4*)(xb + i) = o;
    } else {
        const int e = (b - 1024) * 256 + t;        // < 4096*17 = 69632 exactly
        const int r = e / CPW;
        const int z = e - r * CPW;
        const int target = r * N_IN + z * KCHUNK;
        int lo = 0, hi = N_SPARSE;
        while (lo < hi) { int m = (lo + hi) >> 1; if (idx[m] < target) lo = m + 1; else hi = m; }
        cp[e] = lo;
    }
}

// ---- kernel 2: fused sparse-scatter + MFMA GEMM, split-K -------------------
// Block (bn, bz): K-span = 512 (2 gather-chunks of 256). B-tile built in LDS
// directly from (idx, vals) with XOR swizzle; A fragments loaded straight
// from L2-resident xb (no A staging, no in-loop barriers). bf16 partials.
__global__ __launch_bounds__(512) void fused_gemm(
        const unsigned short* __restrict__ xb,   // 256 x 4096 bf16
        const int* __restrict__ idx,
        const float* __restrict__ vals,
        const int* __restrict__ cp,
        unsigned short* __restrict__ part)       // SPLITK x 256 x 4096 bf16
{
    __shared__ short Bs[BN * KCHUNK];    // 32KB, swizzled sparse tile

    const int tid = threadIdx.x;
    const int l   = tid & 63;
    const int w   = tid >> 6;            // 0..7
    const int bn  = blockIdx.x;          // 0..63
    const int bz  = blockIdx.y;          // 0..7

    const int wm  = w >> 1;              // 0..3 -> 64 M rows each
    const int wn  = w & 1;               // 0..1 -> 32 N cols each
    const int lr  = l & 15;
    const int lkg = l >> 4;              // 0..3
    const int kbase0 = bz * (KCHUNK * NCHUNK);

    // gather indexing (8 threads per B row)
    const int rl   = tid >> 3;           // 0..63 local row
    const int sub  = tid & 7;
    const int rx   = (rl & 7) << 3;
    unsigned short* brow = (unsigned short*)Bs + rl * KCHUNK;
    const int rglob = bn * BN + rl;

    f32x4 acc[4][2] = {};

    for (int c = 0; c < NCHUNK; ++c) {
        // --- zero Bs (16B stores, 32 elems/thread) ---
        {
            const u16x8 z8 = {};
            unsigned short* b0 = (unsigned short*)Bs + tid * 32;
            *(u16x8*)(b0)      = z8; *(u16x8*)(b0 + 8)  = z8;
            *(u16x8*)(b0 + 16) = z8; *(u16x8*)(b0 + 24) = z8;
        }
        __syncthreads();

        // --- sparse gather, 4-wide vector loads, edge-masked ---
        {
            const int seg   = bz * NCHUNK + c;
            const int start = cp[rglob * CPW + seg];
            const int end   = cp[rglob * CPW + seg + 1];
            const int base  = rglob * N_IN + kbase0 + c * KCHUNK;
            for (int jb = (start & ~3) + sub * 4; jb < end; jb += 32) {
                const int4   i4 = *(const int4*)(idx + jb);
                const float4 v4 = *(const float4*)(vals + jb);
                #pragma unroll
                for (int e = 0; e < 4; ++e) {
                    const int j  = jb + e;
                    const int ic = (&i4.x)[e];
                    if (j >= start && j < end) {
                        const int cc = ic - base;          // 0..255
                        brow[((cc & ~7) ^ rx) | (cc & 7)] = f2bf((&v4.x)[e]);
                    }
                }
            }
        }
        __syncthreads();   // Bs ready

        // --- MFMA loop: A from global (L2-hot), B from LDS, no barriers ---
        const unsigned short* ap = xb + kbase0 + c * KCHUNK + lkg * 8;
        #pragma unroll 2
        for (int kk = 0; kk < KCHUNK / 32; ++kk) {   // 8 steps of K=32
            bf16x8 af[4], bfr[2];
            #pragma unroll
            for (int i = 0; i < 4; ++i) {
                const int m = wm * 64 + i * 16 + lr;
                af[i] = *(const bf16x8*)(ap + (size_t)m * N_IN + kk * 32);
            }
            #pragma unroll
            for (int i = 0; i < 2; ++i) {
                const int n    = wn * 32 + i * 16 + lr;
                const int slot = (kk * 4 + lkg) ^ (n & 7);
                bfr[i] = *(const bf16x8*)&Bs[n * KCHUNK + slot * 8];
            }
            #pragma unroll
            for (int mi = 0; mi < 4; ++mi)
                #pragma unroll
                for (int ni = 0; ni < 2; ++ni)
                    acc[mi][ni] = __builtin_amdgcn_mfma_f32_16x16x32_bf16(
                                      af[mi], bfr[ni], acc[mi][ni], 0, 0, 0);
        }
        __syncthreads();   // all waves done reading Bs before re-zero
    }

    // --- epilogue: bf16 partials, C/D layout col=lane&15, row=(l>>4)*4+reg --
    unsigned short* po = part + (size_t)bz * (TOKENS * N_OUT) + (size_t)bn * BN;
    #pragma unroll
    for (int mi = 0; mi < 4; ++mi)
        #pragma unroll
        for (int r = 0; r < 4; ++r) {
            const int m = wm * 64 + mi * 16 + lkg * 4 + r;
            #pragma unroll
            for (int ni = 0; ni < 2; ++ni) {
                const int n = wn * 32 + ni * 16 + lr;
                po[(size_t)m * N_OUT + n] = f2bf(acc[mi][ni][r]);
            }
        }
}

// ---- kernel 3: sum bf16 split-K partials -> f32 out -----------------------
__global__ void reduce_k(const unsigned short* __restrict__ part, float* __restrict__ out) {
    const int i = (blockIdx.x * 256 + threadIdx.x) * 8;
    float a[8] = {};
    for (int z = 0; z < SPLITK; ++z) {
        const u16x8 p = *(const u16x8*)(part + (size_t)z * (TOKENS * N_OUT) + i);
        #pragma unroll
        for (int j = 0; j < 8; ++j) a[j] += bf2f((unsigned short)p[j]);
    }
    float4 o0 = { a[0], a[1], a[2], a[3] };
    float4 o1 = { a[4], a[5], a[6], a[7] };
    *(float4*)(out + i)     = o0;
    *(float4*)(out + i + 4) = o1;
}

// ---- fallback (ws too small): per-output-row CSR, fp32 -------------------
__global__ void fallback_rowcsr(const float* __restrict__ x, const float* __restrict__ vals,
                                const int* __restrict__ idx, float* __restrict__ out) {
    const int o = blockIdx.x;
    const int t = threadIdx.x;
    __shared__ int   scol[256];
    __shared__ float sval[256];

    int lo = 0, hi = N_SPARSE;
    const int target = o * N_IN;
    while (lo < hi) { int m = (lo + hi) >> 1; if (idx[m] < target) lo = m + 1; else hi = m; }
    const int start = lo;
    hi = N_SPARSE;
    const int target2 = target + N_IN;
    while (lo < hi) { int m = (lo + hi) >> 1; if (idx[m] < target2) lo = m + 1; else hi = m; }
    const int end = lo;

    float acc = 0.f;
    const float* xr = x + (size_t)t * N_IN;
    for (int base = start; base < end; base += 256) {
        const int k = base + t;
        if (k < end) { scol[t] = idx[k] - target; sval[t] = vals[k]; }
        __syncthreads();
        const int cnt = min(256, end - base);
        for (int j = 0; j < cnt; ++j) acc += sval[j] * xr[scol[j]];
        __syncthreads();
    }
    out[(size_t)t * N_OUT + o] = acc;
}

extern "C" void kernel_launch(void* const* d_in, const int* in_sizes, int n_in,
                              void* d_out, int out_size, void* d_ws, size_t ws_size,
                              hipStream_t stream) {
    const float* x    = (const float*)d_in[0];
    const float* vals = (const float*)d_in[1];
    const int*   idx  = (const int*)d_in[2];
    float* out = (float*)d_out;

    const size_t part_bytes = (size_t)SPLITK * TOKENS * N_OUT * 2;   // 16 MB
    const size_t xb_bytes   = (size_t)TOKENS * N_IN * 2;             // 2 MB
    const size_t cp_bytes   = (size_t)N_OUT * CPW * 4;               // ~272 KB
    const size_t need = part_bytes + xb_bytes + cp_bytes;            // ~18.3 MB

    if (ws_size >= need) {
        unsigned short* part = (unsigned short*)d_ws;
        unsigned short* xb   = (unsigned short*)((char*)d_ws + part_bytes);
        int*            cp   = (int*)((char*)d_ws + part_bytes + xb_bytes);

        prep<<<1024 + (N_OUT * CPW) / 256, 256, 0, stream>>>(x, idx, xb, cp);
        dim3 grid(N_OUT / BN, SPLITK);
        fused_gemm<<<grid, 512, 0, stream>>>(xb, idx, vals, cp, part);
        reduce_k<<<(TOKENS * N_OUT) / 2048, 256, 0, stream>>>(part, out);
    } else {
        fallback_rowcsr<<<N_OUT, TOKENS, 0, stream>>>(x, vals, idx, out);
    }
}

// Round 10
// 56.366 us; speedup vs baseline: 1.1610x; 1.1610x over previous
//
#include <hip/hip_runtime.h>
#include <stdint.h>

#define N_OUT    4096
#define N_IN     4096
#define TOKENS   256
#define N_SPARSE 8388608
#define SPLITK   16
#define KCHUNK   256               // K-span per block (one segment)
#define NSEG     (N_IN / KCHUNK)   // 16 segments
#define CPW      (NSEG + 1)        // 17 col_ptr entries per row
#define BN       64

typedef __attribute__((ext_vector_type(8))) short bf16x8;
typedef __attribute__((ext_vector_type(8))) unsigned short u16x8;
typedef __attribute__((ext_vector_type(4))) float f32x4;

__device__ __forceinline__ unsigned short f2bf(float f) {
    union { float f; unsigned u; } v; v.f = f;
    unsigned r = v.u + 0x7fffu + ((v.u >> 16) & 1u);   // RNE
    return (unsigned short)(r >> 16);
}

__device__ __forceinline__ float bf2f(unsigned short u) {
    union { unsigned u; float f; } v; v.u = ((unsigned)u) << 16;
    return v.f;
}

// OOB-safe 4-wide load of idx/vals (buffers are exactly page-aligned in size;
// never read past N_SPARSE).
__device__ __forceinline__ void ld4(const int* __restrict__ idx,
                                    const float* __restrict__ vals,
                                    int jb, int4& i4, float4& v4) {
    if (jb + 4 <= N_SPARSE) {
        i4 = *(const int4*)(idx + jb);
        v4 = *(const float4*)(vals + jb);
    } else {
        i4 = int4{0, 0, 0, 0}; v4 = float4{0.f, 0.f, 0.f, 0.f};
        #pragma unroll
        for (int e = 0; e < 4; ++e) {
            const int j = jb + e;
            if (j < N_SPARSE) { (&i4.x)[e] = idx[j]; (&v4.x)[e] = vals[j]; }
        }
    }
}

// ---- kernel 1 (merged): x -> MFMA-fragment-layout bf16  +  col_ptr --------
// Fragment layout: element (m,k) of x lives at
//   xs[ ((k>>5)*16 + (m>>4))*512 + ((m&15) | (((k>>3)&3)<<4))*8 + (k&7) ]
// so an A-fragment load in the GEMM is ONE contiguous 16B/lane (1KB/wave)
// load: base + lane*8, for tile (ktile, mtile).
__global__ void prep(const float* __restrict__ x, const int* __restrict__ idx,
                     unsigned short* __restrict__ xs, int* __restrict__ cp) {
    const int b = blockIdx.x;
    const int t = threadIdx.x;
    if (b < 1024) {
        const int i = (b * 256 + t) * 4;
        const int m = i >> 12;
        const int k = i & 4095;
        const float4 v = *(const float4*)(x + i);
        ushort4 o;
        o.x = f2bf(v.x); o.y = f2bf(v.y); o.z = f2bf(v.z); o.w = f2bf(v.w);
        const int lane = (m & 15) | (((k >> 3) & 3) << 4);
        const int addr = ((k >> 5) * 16 + (m >> 4)) * 512 + lane * 8 + (k & 7);
        *(ushort4*)(xs + addr) = o;     // k..k+3 stay in one 8-elem slot
    } else {
        const int e = (b - 1024) * 256 + t;        // < 4096*17 = 69632 exactly
        const int r = e / CPW;
        const int z = e - r * CPW;
        const int target = r * N_IN + z * KCHUNK;
        int lo = 0, hi = N_SPARSE;
        while (lo < hi) { int m = (lo + hi) >> 1; if (idx[m] < target) lo = m + 1; else hi = m; }
        cp[e] = lo;
    }
}

// ---- kernel 2: fused sparse-scatter + MFMA GEMM, split-K -------------------
// Block (bn, bz): 256 threads / 4 waves. Builds 64x256 bf16 B-tile in LDS
// from (idx, vals) with a software-pipelined 4-wide gather; A fragments come
// straight from the pre-fragmented, L2-resident xs. bf16 partials.
__global__ __launch_bounds__(256) void fused_gemm(
        const unsigned short* __restrict__ xs,
        const int* __restrict__ idx,
        const float* __restrict__ vals,
        const int* __restrict__ cp,
        unsigned short* __restrict__ part)       // SPLITK x 256 x 4096 bf16
{
    __shared__ short Bs[BN * KCHUNK];    // 32KB, swizzled sparse tile

    const int tid = threadIdx.x;
    const int l   = tid & 63;
    const int w   = tid >> 6;            // 0..3 -> 64 M rows each
    const int bn  = blockIdx.x;          // 0..63
    const int bz  = blockIdx.y;          // 0..15

    // --- zero Bs (64 elems/thread, 16B stores) ---
    {
        const u16x8 z8 = {};
        unsigned short* b0 = (unsigned short*)Bs + tid * 64;
        #pragma unroll
        for (int q = 0; q < 8; ++q) *(u16x8*)(b0 + q * 8) = z8;
    }
    __syncthreads();

    // --- sparse gather: 4 threads per B row, software-pipelined 4-wide ---
    {
        const int rl    = tid >> 2;                // 0..63 local row
        const int sub   = tid & 3;
        const int rglob = bn * BN + rl;
        const int start = cp[rglob * CPW + bz];
        const int end   = cp[rglob * CPW + bz + 1];
        const int base  = rglob * N_IN + bz * KCHUNK;
        unsigned short* brow = (unsigned short*)Bs + rl * KCHUNK;
        const int rx = (rl & 7) << 3;

        int jb = (start & ~3) + sub * 4;
        int4 i4; float4 v4;
        bool have = jb < end;
        if (have) ld4(idx, vals, jb, i4, v4);
        while (have) {
            const int jn = jb + 16;
            const bool haven = jn < end;
            int4 i4n; float4 v4n;
            if (haven) ld4(idx, vals, jn, i4n, v4n);   // next iter in flight
            #pragma unroll
            for (int e = 0; e < 4; ++e) {
                const int j = jb + e;
                if (j >= start && j < end) {
                    const int cc = (&i4.x)[e] - base;  // 0..255
                    brow[((cc & ~7) ^ rx) | (cc & 7)] = f2bf((&v4.x)[e]);
                }
            }
            jb = jn; i4 = i4n; v4 = v4n; have = haven;
        }
    }
    __syncthreads();   // Bs ready

    // --- MFMA: A from pre-fragmented xs (L2-hot, 1KB/wave contiguous) ---
    const int lr  = l & 15;
    const int lkg = l >> 4;              // 0..3
    f32x4 acc[4][4] = {};
    const unsigned short* ax = xs + ((size_t)(bz * 8) * 16 + w * 4) * 512 + l * 8;

    #pragma unroll 2
    for (int kk = 0; kk < KCHUNK / 32; ++kk) {       // 8 steps of K=32
        bf16x8 af[4], bfr[4];
        #pragma unroll
        for (int i = 0; i < 4; ++i)
            af[i] = *(const bf16x8*)(ax + (size_t)(kk * 16 + i) * 512);
        #pragma unroll
        for (int i = 0; i < 4; ++i) {
            const int n    = i * 16 + lr;
            const int slot = (kk * 4 + lkg) ^ (n & 7);
            bfr[i] = *(const bf16x8*)&Bs[n * KCHUNK + slot * 8];
        }
        #pragma unroll
        for (int mi = 0; mi < 4; ++mi)
            #pragma unroll
            for (int ni = 0; ni < 4; ++ni)
                acc[mi][ni] = __builtin_amdgcn_mfma_f32_16x16x32_bf16(
                                  af[mi], bfr[ni], acc[mi][ni], 0, 0, 0);
    }

    // --- epilogue: bf16 partials, C/D layout col=lane&15, row=(l>>4)*4+reg --
    unsigned short* po = part + (size_t)bz * (TOKENS * N_OUT) + (size_t)bn * BN;
    #pragma unroll
    for (int mi = 0; mi < 4; ++mi)
        #pragma unroll
        for (int r = 0; r < 4; ++r) {
            const int m = w * 64 + mi * 16 + lkg * 4 + r;
            #pragma unroll
            for (int ni = 0; ni < 4; ++ni) {
                const int n = ni * 16 + lr;
                po[(size_t)m * N_OUT + n] = f2bf(acc[mi][ni][r]);
            }
        }
}

// ---- kernel 3: sum bf16 split-K partials -> f32 out -----------------------
__global__ void reduce_k(const unsigned short* __restrict__ part, float* __restrict__ out) {
    const int i = (blockIdx.x * 256 + threadIdx.x) * 8;
    float a[8] = {};
    for (int z = 0; z < SPLITK; ++z) {
        const u16x8 p = *(const u16x8*)(part + (size_t)z * (TOKENS * N_OUT) + i);
        #pragma unroll
        for (int j = 0; j < 8; ++j) a[j] += bf2f((unsigned short)p[j]);
    }
    float4 o0 = { a[0], a[1], a[2], a[3] };
    float4 o1 = { a[4], a[5], a[6], a[7] };
    *(float4*)(out + i)     = o0;
    *(float4*)(out + i + 4) = o1;
}

// ---- fallback (ws too small): per-output-row CSR, fp32 -------------------
__global__ void fallback_rowcsr(const float* __restrict__ x, const float* __restrict__ vals,
                                const int* __restrict__ idx, float* __restrict__ out) {
    const int o = blockIdx.x;
    const int t = threadIdx.x;
    __shared__ int   scol[256];
    __shared__ float sval[256];

    int lo = 0, hi = N_SPARSE;
    const int target = o * N_IN;
    while (lo < hi) { int m = (lo + hi) >> 1; if (idx[m] < target) lo = m + 1; else hi = m; }
    const int start = lo;
    hi = N_SPARSE;
    const int target2 = target + N_IN;
    while (lo < hi) { int m = (lo + hi) >> 1; if (idx[m] < target2) lo = m + 1; else hi = m; }
    const int end = lo;

    float acc = 0.f;
    const float* xr = x + (size_t)t * N_IN;
    for (int base = start; base < end; base += 256) {
        const int k = base + t;
        if (k < end) { scol[t] = idx[k] - target; sval[t] = vals[k]; }
        __syncthreads();
        const int cnt = min(256, end - base);
        for (int j = 0; j < cnt; ++j) acc += sval[j] * xr[scol[j]];
        __syncthreads();
    }
    out[(size_t)t * N_OUT + o] = acc;
}

extern "C" void kernel_launch(void* const* d_in, const int* in_sizes, int n_in,
                              void* d_out, int out_size, void* d_ws, size_t ws_size,
                              hipStream_t stream) {
    const float* x    = (const float*)d_in[0];
    const float* vals = (const float*)d_in[1];
    const int*   idx  = (const int*)d_in[2];
    float* out = (float*)d_out;

    const size_t part_bytes = (size_t)SPLITK * TOKENS * N_OUT * 2;   // 32 MB
    const size_t xs_bytes   = (size_t)TOKENS * N_IN * 2;             // 2 MB
    const size_t cp_bytes   = (size_t)N_OUT * CPW * 4;               // ~272 KB
    const size_t need = part_bytes + xs_bytes + cp_bytes;            // ~34.3 MB

    if (ws_size >= need) {
        unsigned short* part = (unsigned short*)d_ws;
        unsigned short* xs   = (unsigned short*)((char*)d_ws + part_bytes);
        int*            cp   = (int*)((char*)d_ws + part_bytes + xs_bytes);

        prep<<<1024 + (N_OUT * CPW) / 256, 256, 0, stream>>>(x, idx, xs, cp);
        dim3 grid(N_OUT / BN, SPLITK);
        fused_gemm<<<grid, 256, 0, stream>>>(xs, idx, vals, cp, part);
        reduce_k<<<(TOKENS * N_OUT) / 2048, 256, 0, stream>>>(part, out);
    } else {
        fallback_rowcsr<<<N_OUT, TOKENS, 0, stream>>>(x, vals, idx, out);
    }
}

// Round 11
// 45.681 us; speedup vs baseline: 1.4326x; 1.2339x over previous
//
#include <hip/hip_runtime.h>
#include <stdint.h>

#define N_OUT    4096
#define N_IN     4096
#define TOKENS   256
#define N_SPARSE 8388608
#define SPLITK   8
#define KCHUNK   256               // gather chunk width (one segment)
#define NCHUNK   2                 // segments per block -> K-span 512
#define NSEG     (N_IN / KCHUNK)   // 16 segments
#define CPW      (NSEG + 1)        // 17 col_ptr entries per row
#define BN       64

typedef __attribute__((ext_vector_type(8))) short bf16x8;
typedef __attribute__((ext_vector_type(8))) unsigned short u16x8;
typedef __attribute__((ext_vector_type(4))) float f32x4;

__device__ __forceinline__ unsigned short f2bf(float f) {
    union { float f; unsigned u; } v; v.f = f;
    unsigned r = v.u + 0x7fffu + ((v.u >> 16) & 1u);   // RNE
    return (unsigned short)(r >> 16);
}

__device__ __forceinline__ float bf2f(unsigned short u) {
    union { unsigned u; float f; } v; v.u = ((unsigned)u) << 16;
    return v.f;
}

// OOB-safe 4-wide load of idx/vals (never reads past N_SPARSE).
__device__ __forceinline__ void ld4(const int* __restrict__ idx,
                                    const float* __restrict__ vals,
                                    int jb, int4& i4, float4& v4) {
    if (jb + 4 <= N_SPARSE) {
        i4 = *(const int4*)(idx + jb);
        v4 = *(const float4*)(vals + jb);
    } else {
        i4 = int4{0, 0, 0, 0}; v4 = float4{0.f, 0.f, 0.f, 0.f};
        #pragma unroll
        for (int e = 0; e < 4; ++e) {
            const int j = jb + e;
            if (j < N_SPARSE) { (&i4.x)[e] = idx[j]; (&v4.x)[e] = vals[j]; }
        }
    }
}

__device__ __forceinline__ void consume4(const int4& i4, const float4& v4, int jb,
                                         int start, int end, int base,
                                         unsigned short* __restrict__ brow, int rx) {
    #pragma unroll
    for (int e = 0; e < 4; ++e) {
        const int j = jb + e;
        if (j >= start && j < end) {
            const int cc = (&i4.x)[e] - base;          // 0..255
            brow[((cc & ~7) ^ rx) | (cc & 7)] = f2bf((&v4.x)[e]);
        }
    }
}

// ---- kernel 1 (merged): x -> MFMA-fragment-layout bf16  +  col_ptr --------
// Fragment layout: element (m,k) of x lives at
//   xs[ ((k>>5)*16 + (m>>4))*512 + ((m&15) | (((k>>3)&3)<<4))*8 + (k&7) ]
// so an A-fragment load in the GEMM is ONE contiguous 16B/lane (1KB/wave).
__global__ void prep(const float* __restrict__ x, const int* __restrict__ idx,
                     unsigned short* __restrict__ xs, int* __restrict__ cp) {
    const int b = blockIdx.x;
    const int t = threadIdx.x;
    if (b < 1024) {
        const int i = (b * 256 + t) * 4;
        const int m = i >> 12;
        const int k = i & 4095;
        const float4 v = *(const float4*)(x + i);
        ushort4 o;
        o.x = f2bf(v.x); o.y = f2bf(v.y); o.z = f2bf(v.z); o.w = f2bf(v.w);
        const int lane = (m & 15) | (((k >> 3) & 3) << 4);
        const int addr = ((k >> 5) * 16 + (m >> 4)) * 512 + lane * 8 + (k & 7);
        *(ushort4*)(xs + addr) = o;     // k..k+3 stay in one 8-elem slot
    } else {
        const int e = (b - 1024) * 256 + t;        // < 4096*17 = 69632 exactly
        const int r = e / CPW;
        const int z = e - r * CPW;
        const int target = r * N_IN + z * KCHUNK;
        int lo = 0, hi = N_SPARSE;
        while (lo < hi) { int m = (lo + hi) >> 1; if (idx[m] < target) lo = m + 1; else hi = m; }
        cp[e] = lo;
    }
}

// ---- kernel 2: fused sparse-scatter + MFMA GEMM, split-K -------------------
// Block (bn, bz): 512 threads / 8 waves, K-span 512 (2 segments of 256).
// Per segment: zero Bs -> 4-deep-pipelined gather into swizzled LDS tile ->
// MFMA (A from pre-fragmented L2-resident xs, B from LDS). bf16 partials.
__global__ __launch_bounds__(512) void fused_gemm(
        const unsigned short* __restrict__ xs,
        const int* __restrict__ idx,
        const float* __restrict__ vals,
        const int* __restrict__ cp,
        unsigned short* __restrict__ part)       // SPLITK x 256 x 4096 bf16
{
    __shared__ short Bs[BN * KCHUNK];    // 32KB, swizzled sparse tile

    const int tid = threadIdx.x;
    const int l   = tid & 63;
    const int w   = tid >> 6;            // 0..7 -> 32 M rows each
    const int bn  = blockIdx.x;          // 0..63
    const int bz  = blockIdx.y;          // 0..7

    // gather indexing: 8 threads per B row
    const int rl    = tid >> 3;          // 0..63 local row
    const int sub   = tid & 7;
    const int rglob = bn * BN + rl;
    const int rx    = (rl & 7) << 3;
    unsigned short* brow = (unsigned short*)Bs + rl * KCHUNK;

    const int lr  = l & 15;
    const int lkg = l >> 4;              // 0..3
    f32x4 acc[2][4] = {};

    #pragma unroll
    for (int c = 0; c < NCHUNK; ++c) {
        const int seg = bz * NCHUNK + c;

        // --- zero Bs (32 elems/thread, 16B stores) ---
        {
            const u16x8 z8 = {};
            unsigned short* b0 = (unsigned short*)Bs + tid * 32;
            #pragma unroll
            for (int q = 0; q < 4; ++q) *(u16x8*)(b0 + q * 8) = z8;
        }
        __syncthreads();

        // --- sparse gather: 4-deep static pipeline, buffers reload in place ---
        {
            const int start = cp[rglob * CPW + seg];
            const int end   = cp[rglob * CPW + seg + 1];
            const int base  = rglob * N_IN + seg * KCHUNK;

            int ja = (start & ~3) + sub * 4;
            int jb_ = ja + 32, jc = ja + 64, jd = ja + 96;
            int4 ia, ib, ic, id; float4 va, vb, vc, vd;
            if (ja  < end) ld4(idx, vals, ja,  ia, va);
            if (jb_ < end) ld4(idx, vals, jb_, ib, vb);
            if (jc  < end) ld4(idx, vals, jc,  ic, vc);
            if (jd  < end) ld4(idx, vals, jd,  id, vd);
            while (ja < end) {
                consume4(ia, va, ja, start, end, base, brow, rx);
                ja += 128; if (ja < end) ld4(idx, vals, ja, ia, va);
                if (jb_ < end) {
                    consume4(ib, vb, jb_, start, end, base, brow, rx);
                    jb_ += 128; if (jb_ < end) ld4(idx, vals, jb_, ib, vb);
                }
                if (jc < end) {
                    consume4(ic, vc, jc, start, end, base, brow, rx);
                    jc += 128; if (jc < end) ld4(idx, vals, jc, ic, vc);
                }
                if (jd < end) {
                    consume4(id, vd, jd, start, end, base, brow, rx);
                    jd += 128; if (jd < end) ld4(idx, vals, jd, id, vd);
                }
            }
        }
        __syncthreads();   // Bs ready

        // --- MFMA: A from pre-fragmented xs (L2-hot, 1KB/wave contiguous) ---
        const unsigned short* ax = xs + ((size_t)(seg * 8) * 16) * 512 + l * 8;
        #pragma unroll 2
        for (int kk = 0; kk < KCHUNK / 32; ++kk) {       // 8 steps of K=32
            bf16x8 af[2], bfr[4];
            #pragma unroll
            for (int i = 0; i < 2; ++i)
                af[i] = *(const bf16x8*)(ax + (size_t)(kk * 16 + w * 2 + i) * 512);
            #pragma unroll
            for (int i = 0; i < 4; ++i) {
                const int n    = i * 16 + lr;
                const int slot = (kk * 4 + lkg) ^ (n & 7);
                bfr[i] = *(const bf16x8*)&Bs[n * KCHUNK + slot * 8];
            }
            #pragma unroll
            for (int mi = 0; mi < 2; ++mi)
                #pragma unroll
                for (int ni = 0; ni < 4; ++ni)
                    acc[mi][ni] = __builtin_amdgcn_mfma_f32_16x16x32_bf16(
                                      af[mi], bfr[ni], acc[mi][ni], 0, 0, 0);
        }
        __syncthreads();   // all waves done reading Bs before re-zero
    }

    // --- epilogue: bf16 partials, C/D layout col=lane&15, row=(l>>4)*4+reg --
    unsigned short* po = part + (size_t)bz * (TOKENS * N_OUT) + (size_t)bn * BN;
    #pragma unroll
    for (int mi = 0; mi < 2; ++mi)
        #pragma unroll
        for (int r = 0; r < 4; ++r) {
            const int m = w * 32 + mi * 16 + lkg * 4 + r;
            #pragma unroll
            for (int ni = 0; ni < 4; ++ni) {
                const int n = ni * 16 + lr;
                po[(size_t)m * N_OUT + n] = f2bf(acc[mi][ni][r]);
            }
        }
}

// ---- kernel 3: sum bf16 split-K partials -> f32 out -----------------------
__global__ void reduce_k(const unsigned short* __restrict__ part, float* __restrict__ out) {
    const int i = (blockIdx.x * 256 + threadIdx.x) * 8;
    float a[8] = {};
    for (int z = 0; z < SPLITK; ++z) {
        const u16x8 p = *(const u16x8*)(part + (size_t)z * (TOKENS * N_OUT) + i);
        #pragma unroll
        for (int j = 0; j < 8; ++j) a[j] += bf2f((unsigned short)p[j]);
    }
    float4 o0 = { a[0], a[1], a[2], a[3] };
    float4 o1 = { a[4], a[5], a[6], a[7] };
    *(float4*)(out + i)     = o0;
    *(float4*)(out + i + 4) = o1;
}

// ---- fallback (ws too small): per-output-row CSR, fp32 -------------------
__global__ void fallback_rowcsr(const float* __restrict__ x, const float* __restrict__ vals,
                                const int* __restrict__ idx, float* __restrict__ out) {
    const int o = blockIdx.x;
    const int t = threadIdx.x;
    __shared__ int   scol[256];
    __shared__ float sval[256];

    int lo = 0, hi = N_SPARSE;
    const int target = o * N_IN;
    while (lo < hi) { int m = (lo + hi) >> 1; if (idx[m] < target) lo = m + 1; else hi = m; }
    const int start = lo;
    hi = N_SPARSE;
    const int target2 = target + N_IN;
    while (lo < hi) { int m = (lo + hi) >> 1; if (idx[m] < target2) lo = m + 1; else hi = m; }
    const int end = lo;

    float acc = 0.f;
    const float* xr = x + (size_t)t * N_IN;
    for (int base = start; base < end; base += 256) {
        const int k = base + t;
        if (k < end) { scol[t] = idx[k] - target; sval[t] = vals[k]; }
        __syncthreads();
        const int cnt = min(256, end - base);
        for (int j = 0; j < cnt; ++j) acc += sval[j] * xr[scol[j]];
        __syncthreads();
    }
    out[(size_t)t * N_OUT + o] = acc;
}

extern "C" void kernel_launch(void* const* d_in, const int* in_sizes, int n_in,
                              void* d_out, int out_size, void* d_ws, size_t ws_size,
                              hipStream_t stream) {
    const float* x    = (const float*)d_in[0];
    const float* vals = (const float*)d_in[1];
    const int*   idx  = (const int*)d_in[2];
    float* out = (float*)d_out;

    const size_t part_bytes = (size_t)SPLITK * TOKENS * N_OUT * 2;   // 16 MB
    const size_t xs_bytes   = (size_t)TOKENS * N_IN * 2;             // 2 MB
    const size_t cp_bytes   = (size_t)N_OUT * CPW * 4;               // ~272 KB
    const size_t need = part_bytes + xs_bytes + cp_bytes;            // ~18.3 MB

    if (ws_size >= need) {
        unsigned short* part = (unsigned short*)d_ws;
        unsigned short* xs   = (unsigned short*)((char*)d_ws + part_bytes);
        int*            cp   = (int*)((char*)d_ws + part_bytes + xs_bytes);

        prep<<<1024 + (N_OUT * CPW) / 256, 256, 0, stream>>>(x, idx, xs, cp);
        dim3 grid(N_OUT / BN, SPLITK);
        fused_gemm<<<grid, 512, 0, stream>>>(xs, idx, vals, cp, part);
        reduce_k<<<(TOKENS * N_OUT) / 2048, 256, 0, stream>>>(part, out);
    } else {
        fallback_rowcsr<<<N_OUT, TOKENS, 0, stream>>>(x, vals, idx, out);
    }
}